// Round 6
// baseline (517.284 us; speedup 1.0000x reference)
//
#include <hip/hip_runtime.h>
#include <stdint.h>

#define N_NODES 50000
#define N_EDGES 1600000
#define HID 128
#define NB 196      // dst buckets of 256 nodes
#define CHUNK 8192
#define NCH 196     // ceil(1600000 / 8192)
#define TOT (NB * NCH)
#define SCAN_J 152  // ceil(TOT/256)

typedef float f32x4 __attribute__((ext_vector_type(4)));
typedef short s16x8 __attribute__((ext_vector_type(8)));
typedef unsigned u32x4 __attribute__((ext_vector_type(4)));

__device__ __forceinline__ unsigned short f2bf(float f) {
  unsigned u = __float_as_uint(f);
  u += 0x7fffu + ((u >> 16) & 1u);   // RNE
  return (unsigned short)(u >> 16);
}

// ---- W transpose + convert: Wt[l][r][k][d] = W[l][r][d][k] (r=8 -> W_loop) ----
__global__ void k_convert_w(const float* __restrict__ W, const float* __restrict__ Wl,
                            unsigned short* __restrict__ Wt) {
  int idx = blockIdx.x * 256 + threadIdx.x;   // (((l*9+r)*128)+k)*128+d
  int d  = idx & 127;
  int k  = (idx >> 7) & 127;
  int lr = idx >> 14;                          // l*9 + r
  int l = lr / 9, r = lr - l * 9;
  float v;
  if (r < 8) v = W[((((size_t)l * 8 + r) * 128) + d) * 128 + k];
  else       v = Wl[(((size_t)l * 128) + d) * 128 + k];
  Wt[idx] = f2bf(v);
}

// ---- h0 = bf16(emb[node_id]) ----
__global__ void k_gather_h0(const int* __restrict__ nid, const float* __restrict__ emb,
                            unsigned short* __restrict__ h0) {
  int t = blockIdx.x * 256 + threadIdx.x;      // N*32 threads, 4 elems each
  int i = t >> 5, c = (t & 31) * 4;
  if (i >= N_NODES) return;
  const float4 v = *(const float4*)(emb + (size_t)nid[i] * HID + c);
  ushort4 o;
  o.x = f2bf(v.x); o.y = f2bf(v.y); o.z = f2bf(v.z); o.w = f2bf(v.w);
  *(ushort4*)(h0 + (size_t)i * HID + c) = o;
}

__device__ __forceinline__ int block_scan_excl(int v, int t) {
  const int lane = t & 63, wid = t >> 6;
  int incl = v;
  #pragma unroll
  for (int o = 1; o < 64; o <<= 1) {
    int nv = __shfl_up(incl, o);
    if (lane >= o) incl += nv;
  }
  __shared__ int wsum[4];
  if (lane == 63) wsum[wid] = incl;
  __syncthreads();
  int wbase = 0;
  #pragma unroll
  for (int w = 0; w < 3; ++w) if (w < wid) wbase += wsum[w];
  return wbase + incl - v;
}

// ---- CSR pass A: per-chunk bucket histogram -> TRANSPOSED store histT[b][c] ----
__global__ void k_chunk_hist(const int* __restrict__ dst, int* __restrict__ histT) {
  __shared__ int h[NB];
  const int c = blockIdx.x, t = threadIdx.x;
  if (t < NB) h[t] = 0;
  __syncthreads();
  int base = c * CHUNK;
  #pragma unroll 4
  for (int i = t; i < CHUNK; i += 256) {
    int e = base + i;
    if (e < N_EDGES) atomicAdd(&h[dst[e] >> 8], 1);
  }
  __syncthreads();
  if (t < NB) histT[t * NCH + c] = h[t];
}

// ---- CSR pass B: scan 38416 counters (contiguous in bucket-major layout) ----
__global__ void k_csr_scan(const int* __restrict__ histT, int* __restrict__ cur,
                           int* __restrict__ bbase, int* __restrict__ rowptr2) {
  const int t = threadIdx.x;
  const int lo = t * SCAN_J;
  int s = 0;
  #pragma unroll 8
  for (int j = 0; j < SCAN_J; ++j) {
    int idx = lo + j;
    if (idx < TOT) s += histT[idx];
  }
  int run = block_scan_excl(s, t);
  #pragma unroll 4
  for (int j = 0; j < SCAN_J; ++j) {
    int idx = lo + j;                    // idx = b*NCH + c
    if (idx < TOT) {
      int b = idx / NCH, c = idx - b * NCH;
      cur[c * NB + b] = run;
      if (c == 0) bbase[b] = run;
      run += histT[idx];
    }
  }
  if (t == 0) { bbase[NB] = N_EDGES; rowptr2[(size_t)N_NODES * 8] = N_EDGES; }
}

// ---- CSR pass C: chunk-local scatter via LDS cursors (no global atomics) ----
// record = (dst&255)<<19 | et<<16 | src
__global__ void k_chunk_scatter(const int* __restrict__ src, const int* __restrict__ dst,
                                const int* __restrict__ et, const int* __restrict__ cur,
                                unsigned* __restrict__ tmp) {
  __shared__ int off2[NB];
  const int c = blockIdx.x, t = threadIdx.x;
  if (t < NB) off2[t] = cur[c * NB + t];
  __syncthreads();
  int base = c * CHUNK;
  #pragma unroll 4
  for (int i = t; i < CHUNK; i += 256) {
    int e = base + i;
    if (e < N_EDGES) {
      int d = dst[e];
      int pos = atomicAdd(&off2[d >> 8], 1);
      tmp[pos] = ((unsigned)(d & 255) << 19) | ((unsigned)et[e] << 16) | (unsigned)src[e];
    }
  }
}

// ---- CSR finalize: per-(node,rel) counting sort -> rowptr2 + ushort keys ----
__global__ void k_bucket_finalize(const unsigned* __restrict__ tmp,
                                  const int* __restrict__ bbase,
                                  int* __restrict__ rowptr2,
                                  unsigned short* __restrict__ keys) {
  __shared__ int cnt2[2048];
  __shared__ int off2[2048];
  const int b = blockIdx.x;
  const int t = threadIdx.x;
  const int s = bbase[b], e = bbase[b + 1];
  for (int i = t; i < 2048; i += 256) cnt2[i] = 0;
  __syncthreads();
  for (int i = s + t; i < e; i += 256) {
    unsigned r = tmp[i];
    atomicAdd(&cnt2[((r >> 19) & 255u) * 8 + ((r >> 16) & 7u)], 1);
  }
  __syncthreads();
  int v8[8]; int sum = 0;
  #pragma unroll
  for (int j = 0; j < 8; ++j) { v8[j] = cnt2[t * 8 + j]; sum += v8[j]; }
  int ex = block_scan_excl(sum, t);
  int run = s + ex;
  int node = b * 256 + t;
  #pragma unroll
  for (int j = 0; j < 8; ++j) {
    if (node < N_NODES) rowptr2[(size_t)node * 8 + j] = run;
    off2[t * 8 + j] = run;
    run += v8[j];
  }
  __syncthreads();
  for (int i = s + t; i < e; i += 256) {
    unsigned r = tmp[i];
    int pos = atomicAdd(&off2[((r >> 19) & 255u) * 8 + ((r >> 16) & 7u)], 1);
    keys[pos] = (unsigned short)(r & 0xffffu);
  }
}

// ---- per-(node,rel) aggregation: one wave per SEGMENT (400K waves) ----
// S[r][v][:] = sum_{e in seg(v,r)} h[src_e]   (bf16, nt-stored)
__global__ void k_agg(const unsigned short* __restrict__ h,
                      const unsigned short* __restrict__ keys,
                      const int* __restrict__ rowptr2,
                      unsigned short* __restrict__ S) {
  const int t = threadIdx.x;
  const int sid = blockIdx.x * 4 + (t >> 6);   // = r * N_NODES + v  (r-major)
  const int lane = t & 63;
  const int r = sid / N_NODES;
  const int v = sid - r * N_NODES;
  const int sp = v * 8 + r;                    // rowptr2 is node-major
  const int e0 = rowptr2[sp], e1 = rowptr2[sp + 1];
  const unsigned char* hB = (const unsigned char*)h;
  float a0 = 0.f, a1 = 0.f;
  int e = e0;
  const int e4 = e0 + ((e1 - e0) & ~3);
  for (; e < e4; e += 4) {
    unsigned s0 = keys[e], s1 = keys[e + 1], s2 = keys[e + 2], s3 = keys[e + 3];
    unsigned p0 = *(const unsigned*)(hB + ((size_t)s0 << 8) + lane * 4);
    unsigned p1 = *(const unsigned*)(hB + ((size_t)s1 << 8) + lane * 4);
    unsigned p2 = *(const unsigned*)(hB + ((size_t)s2 << 8) + lane * 4);
    unsigned p3 = *(const unsigned*)(hB + ((size_t)s3 << 8) + lane * 4);
    a0 += __uint_as_float(p0 << 16); a1 += __uint_as_float(p0 & 0xffff0000u);
    a0 += __uint_as_float(p1 << 16); a1 += __uint_as_float(p1 & 0xffff0000u);
    a0 += __uint_as_float(p2 << 16); a1 += __uint_as_float(p2 & 0xffff0000u);
    a0 += __uint_as_float(p3 << 16); a1 += __uint_as_float(p3 & 0xffff0000u);
  }
  for (; e < e1; ++e) {
    unsigned s0 = keys[e];
    unsigned p0 = *(const unsigned*)(hB + ((size_t)s0 << 8) + lane * 4);
    a0 += __uint_as_float(p0 << 16); a1 += __uint_as_float(p0 & 0xffff0000u);
  }
  unsigned pk = ((unsigned)f2bf(a1) << 16) | (unsigned)f2bf(a0);
  __builtin_nontemporal_store(
      pk, (unsigned*)((unsigned char*)S + (((size_t)sid) << 8) + lane * 4));
}

// ---- transform: out = sum_{r<8} S_r @ Wt_r + h @ Wt_8 + bias ----
template <bool LAST>
__global__ __launch_bounds__(256, 3) void k_gemm2(
    const unsigned short* __restrict__ S,    // [8][N][128] bf16
    const unsigned short* __restrict__ h,    // [N][128] bf16
    const unsigned short* __restrict__ Wt,   // [9][128][128] bf16 (this layer)
    const float* __restrict__ bias,
    void* __restrict__ out) {
  __shared__ unsigned char As[64 * 256];   // 16KB
  __shared__ unsigned char Bs[128 * 256];  // 32KB
  const int t = threadIdx.x, wid = t >> 6, lane = t & 63;
  const int nb = blockIdx.x * 64;
  const int lr = lane & 15, kg = (lane >> 4) * 8;
  f32x4 C[8];
  #pragma unroll
  for (int n = 0; n < 8; ++n) C[n] = (f32x4)(0.f);

  for (int r = 0; r < 9; ++r) {
    const unsigned char* Asrc = (r < 8)
        ? (const unsigned char*)(S + (size_t)r * N_NODES * 128)
        : (const unsigned char*)h;
    // stage A-tile (16KB): rows nb..nb+63, swizzled; S read non-temporally
    #pragma unroll
    for (int c = 0; c < 4; ++c) {
      int off = c * 4096 + t * 16;
      int row = off >> 8, ib = off & 255;
      int grow = nb + row;
      u32x4 va = (u32x4)(0u);
      if (grow < N_NODES) {
        const u32x4* p = (const u32x4*)(Asrc + (size_t)grow * 256 + ib);
        va = (r < 8) ? __builtin_nontemporal_load(p) : *p;
      }
      *(u32x4*)(As + row * 256 + (ib ^ ((row & 7) << 4))) = va;
    }
    // stage B = Wt_r (32KB), swizzled (cached: shared by all blocks)
    const unsigned char* Bsrc = (const unsigned char*)(Wt + (size_t)r * 16384);
    #pragma unroll
    for (int c = 0; c < 8; ++c) {
      int off = c * 4096 + t * 16;
      int row = off >> 8, ib = off & 255;
      *(u32x4*)(Bs + row * 256 + (ib ^ ((row & 7) << 4))) = *(const u32x4*)(Bsrc + off);
    }
    __syncthreads();
    #pragma unroll
    for (int kk = 0; kk < 4; ++kk) {
      int kb = (kk * 32 + kg) * 2;
      int rA = wid * 16 + lr;
      s16x8 a = *(const s16x8*)(As + rA * 256 + (kb ^ ((rA & 7) << 4)));
      #pragma unroll
      for (int n = 0; n < 8; ++n) {
        int cc = n * 16 + lr;
        s16x8 b = *(const s16x8*)(Bs + cc * 256 + (kb ^ ((cc & 7) << 4)));
        C[n] = __builtin_amdgcn_mfma_f32_16x16x32_bf16(a, b, C[n], 0, 0, 0);
      }
    }
    __syncthreads();
  }
  // epilogue: C layout col=lane&15, row=(lane>>4)*4+j
  const int rbase = nb + wid * 16 + (lane >> 4) * 4;
  if (LAST) {
    float* o = (float*)out;
    #pragma unroll
    for (int n = 0; n < 8; ++n) {
      int col = n * 16 + lr;
      float bv = bias[col];
      #pragma unroll
      for (int j = 0; j < 4; ++j) {
        int v = rbase + j;
        if (v < N_NODES)
          __builtin_nontemporal_store(C[n][j] + bv, &o[(size_t)v * 128 + col]);
      }
    }
  } else {
    unsigned short* o = (unsigned short*)out;
    #pragma unroll
    for (int n = 0; n < 8; ++n) {
      int col = n * 16 + lr;
      float bv = bias[col];
      #pragma unroll
      for (int j = 0; j < 4; ++j) {
        int v = rbase + j;
        if (v < N_NODES) o[(size_t)v * 128 + col] = f2bf(C[n][j] + bv);
      }
    }
  }
}

extern "C" void kernel_launch(void* const* d_in, const int* in_sizes, int n_in,
                              void* d_out, int out_size, void* d_ws, size_t ws_size,
                              hipStream_t stream) {
  const int*   nid  = (const int*)d_in[0];
  const int*   src  = (const int*)d_in[1];
  const int*   dst  = (const int*)d_in[2];
  const int*   et   = (const int*)d_in[3];
  const float* emb  = (const float*)d_in[4];
  const float* W    = (const float*)d_in[5];
  const float* Wl   = (const float*)d_in[6];
  const float* bias = (const float*)d_in[7];

  unsigned char* ws = (unsigned char*)d_ws;
  size_t off = 0;
  auto alloc = [&](size_t bytes) {
    void* p = ws + off;
    off = (off + bytes + 255) & ~(size_t)255;
    return p;
  };
  unsigned short* S     = (unsigned short*)alloc((size_t)8 * N_NODES * HID * 2);  // 102.4 MB
  unsigned short* h0    = (unsigned short*)alloc((size_t)N_NODES * HID * 2);      // 12.8 MB
  unsigned short* h1    = (unsigned short*)alloc((size_t)N_NODES * HID * 2);      // 12.8 MB
  unsigned short* Wt    = (unsigned short*)alloc((size_t)2 * 9 * 128 * 128 * 2);  // 0.6 MB
  unsigned short* keys  = (unsigned short*)alloc((size_t)N_EDGES * 2);            // 3.2 MB
  unsigned*       tmp   = (unsigned*)S;    // S dead during CSR build; reuse as scratch
  int*            rowp2 = (int*)alloc(((size_t)N_NODES * 8 + 1) * 4);             // 1.6 MB
  int*            histT = (int*)alloc((size_t)TOT * 4);                           // 150 KB
  int*            cur   = (int*)alloc((size_t)TOT * 4);                           // 150 KB
  int*            bbas  = (int*)alloc((size_t)(NB + 1) * 4);

  k_convert_w<<<1152, 256, 0, stream>>>(W, Wl, Wt);
  k_gather_h0<<<(N_NODES * 32) / 256, 256, 0, stream>>>(nid, emb, h0);
  k_chunk_hist<<<NCH, 256, 0, stream>>>(dst, histT);
  k_csr_scan<<<1, 256, 0, stream>>>(histT, cur, bbas, rowp2);
  k_chunk_scatter<<<NCH, 256, 0, stream>>>(src, dst, et, cur, tmp);
  k_bucket_finalize<<<NB, 256, 0, stream>>>(tmp, bbas, rowp2, keys);

  const int agrid = (N_NODES * 8) / 4;           // 100000 blocks, 1 wave/segment
  const int ggrid = (N_NODES + 63) / 64;         // 782
  // layer 0
  k_agg<<<agrid, 256, 0, stream>>>(h0, keys, rowp2, S);
  k_gemm2<false><<<ggrid, 256, 0, stream>>>(S, h0, Wt, bias, (void*)h1);
  // layer 1
  k_agg<<<agrid, 256, 0, stream>>>(h1, keys, rowp2, S);
  k_gemm2<true><<<ggrid, 256, 0, stream>>>(S, h1, Wt + (size_t)9 * 128 * 128,
                                           bias + HID, (void*)d_out);
}

// Round 8
// 373.098 us; speedup vs baseline: 1.3865x; 1.3865x over previous
//
#include <hip/hip_runtime.h>
#include <stdint.h>

#define N_NODES 50000
#define N_EDGES 1600000
#define HID 128
#define NB 196      // dst buckets of 256 nodes
#define CHUNK 8192
#define NCH 196     // ceil(1600000 / 8192)
#define TOT (NB * NCH)
#define SCAN_J 152  // ceil(TOT/256)

typedef float f32x4 __attribute__((ext_vector_type(4)));
typedef float f32x2 __attribute__((ext_vector_type(2)));
typedef short s16x8 __attribute__((ext_vector_type(8)));
typedef unsigned u32x4 __attribute__((ext_vector_type(4)));

__device__ __forceinline__ unsigned short f2bf(float f) {
  unsigned u = __float_as_uint(f);
  u += 0x7fffu + ((u >> 16) & 1u);   // RNE
  return (unsigned short)(u >> 16);
}

// ---- W transpose + convert: Wt[l][r][k][d] = W[l][r][d][k] (r=8 -> W_loop) ----
__global__ void k_convert_w(const float* __restrict__ W, const float* __restrict__ Wl,
                            unsigned short* __restrict__ Wt) {
  int idx = blockIdx.x * 256 + threadIdx.x;   // (((l*9+r)*128)+k)*128+d
  int d  = idx & 127;
  int k  = (idx >> 7) & 127;
  int lr = idx >> 14;                          // l*9 + r
  int l = lr / 9, r = lr - l * 9;
  float v;
  if (r < 8) v = W[((((size_t)l * 8 + r) * 128) + d) * 128 + k];
  else       v = Wl[(((size_t)l * 128) + d) * 128 + k];
  Wt[idx] = f2bf(v);
}

// ---- h0 = bf16(emb[node_id]) ----
__global__ void k_gather_h0(const int* __restrict__ nid, const float* __restrict__ emb,
                            unsigned short* __restrict__ h0) {
  int t = blockIdx.x * 256 + threadIdx.x;      // N*32 threads, 4 elems each
  int i = t >> 5, c = (t & 31) * 4;
  if (i >= N_NODES) return;
  const float4 v = *(const float4*)(emb + (size_t)nid[i] * HID + c);
  ushort4 o;
  o.x = f2bf(v.x); o.y = f2bf(v.y); o.z = f2bf(v.z); o.w = f2bf(v.w);
  *(ushort4*)(h0 + (size_t)i * HID + c) = o;
}

__device__ __forceinline__ int block_scan_excl(int v, int t) {
  const int lane = t & 63, wid = t >> 6;
  int incl = v;
  #pragma unroll
  for (int o = 1; o < 64; o <<= 1) {
    int nv = __shfl_up(incl, o);
    if (lane >= o) incl += nv;
  }
  __shared__ int wsum[4];
  if (lane == 63) wsum[wid] = incl;
  __syncthreads();
  int wbase = 0;
  #pragma unroll
  for (int w = 0; w < 3; ++w) if (w < wid) wbase += wsum[w];
  return wbase + incl - v;
}

// ---- CSR pass A: per-chunk bucket histogram -> TRANSPOSED store histT[b][c] ----
__global__ void k_chunk_hist(const int* __restrict__ dst, int* __restrict__ histT) {
  __shared__ int h[NB];
  const int c = blockIdx.x, t = threadIdx.x;
  if (t < NB) h[t] = 0;
  __syncthreads();
  int base = c * CHUNK;
  #pragma unroll 4
  for (int i = t; i < CHUNK; i += 256) {
    int e = base + i;
    if (e < N_EDGES) atomicAdd(&h[dst[e] >> 8], 1);
  }
  __syncthreads();
  if (t < NB) histT[t * NCH + c] = h[t];
}

// ---- CSR pass B: scan 38416 counters (contiguous in bucket-major layout) ----
__global__ void k_csr_scan(const int* __restrict__ histT, int* __restrict__ cur,
                           int* __restrict__ bbase, int* __restrict__ rowptr) {
  const int t = threadIdx.x;
  const int lo = t * SCAN_J;
  int s = 0;
  #pragma unroll 8
  for (int j = 0; j < SCAN_J; ++j) {
    int idx = lo + j;
    if (idx < TOT) s += histT[idx];
  }
  int run = block_scan_excl(s, t);
  #pragma unroll 4
  for (int j = 0; j < SCAN_J; ++j) {
    int idx = lo + j;                    // idx = b*NCH + c
    if (idx < TOT) {
      int b = idx / NCH, c = idx - b * NCH;
      cur[c * NB + b] = run;
      if (c == 0) bbase[b] = run;
      run += histT[idx];
    }
  }
  if (t == 0) { bbase[NB] = N_EDGES; rowptr[N_NODES] = N_EDGES; }
}

// ---- CSR pass C: chunk-local scatter via LDS cursors (no global atomics) ----
// record = (dst&255)<<19 | et<<16 | src
__global__ void k_chunk_scatter(const int* __restrict__ src, const int* __restrict__ dst,
                                const int* __restrict__ et, const int* __restrict__ cur,
                                unsigned* __restrict__ tmp) {
  __shared__ int off2[NB];
  const int c = blockIdx.x, t = threadIdx.x;
  if (t < NB) off2[t] = cur[c * NB + t];
  __syncthreads();
  int base = c * CHUNK;
  #pragma unroll 4
  for (int i = t; i < CHUNK; i += 256) {
    int e = base + i;
    if (e < N_EDGES) {
      int d = dst[e];
      int pos = atomicAdd(&off2[d >> 8], 1);
      tmp[pos] = ((unsigned)(d & 255) << 19) | ((unsigned)et[e] << 16) | (unsigned)src[e];
    }
  }
}

// ---- CSR finalize: per-node counting sort -> rowptr + u32 keys (et*N+src) ----
__global__ void k_bucket_finalize(const unsigned* __restrict__ tmp,
                                  const int* __restrict__ bbase,
                                  int* __restrict__ rowptr,
                                  unsigned* __restrict__ keys) {
  __shared__ int cnt[256];
  __shared__ int off[256];
  const int b = blockIdx.x;
  const int t = threadIdx.x;
  const int s = bbase[b], e = bbase[b + 1];
  cnt[t] = 0;
  __syncthreads();
  for (int i = s + t; i < e; i += 256)
    atomicAdd(&cnt[(tmp[i] >> 19) & 255u], 1);
  __syncthreads();
  int ex = block_scan_excl(cnt[t], t);
  int node = b * 256 + t;
  if (node < N_NODES) rowptr[node] = s + ex;
  off[t] = s + ex;
  __syncthreads();
  for (int i = s + t; i < e; i += 256) {
    unsigned r = tmp[i];
    int pos = atomicAdd(&off[(r >> 19) & 255u], 1);
    keys[pos] = ((r >> 16) & 7u) * N_NODES + (r & 0xffffu);
  }
}

// ---- GEMM: X[rel][n][k] = sum_d A[n][d] * Wt[rel][k][d], bf16 in/out, f32 acc ----
__global__ __launch_bounds__(256, 2) void k_gemm(
    const unsigned short* __restrict__ A,   // [N][128] bf16
    const unsigned short* __restrict__ Bw,  // [9][128][128] bf16 (this layer's Wt)
    unsigned short* __restrict__ X) {       // [9][N][128] bf16
  __shared__ unsigned char lds[65536];
  unsigned char* As = lds;
  unsigned char* Bs = lds + 32768;
  const int t   = threadIdx.x;
  const int rel = blockIdx.x;
  const int mb  = blockIdx.y;
  const unsigned char* Asrc = (const unsigned char*)A;
  const unsigned char* Bsrc = (const unsigned char*)(Bw + (size_t)rel * (128 * 128));
  #pragma unroll
  for (int c = 0; c < 8; ++c) {
    int off = c * 4096 + t * 16;
    int row = off >> 8;
    int ib  = off & 255;
    int swz = ib ^ ((row & 7) << 4);
    int grow = mb * 128 + row;
    u32x4 va = (u32x4)(0u);
    if (grow < N_NODES) va = *(const u32x4*)(Asrc + (size_t)grow * 256 + ib);
    *(u32x4*)(As + row * 256 + swz) = va;
    u32x4 vb = *(const u32x4*)(Bsrc + off);
    *(u32x4*)(Bs + row * 256 + swz) = vb;
  }
  __syncthreads();
  const int wid = t >> 6, lane = t & 63;
  const int row0 = wid * 32;
  const int lr = lane & 15;
  const int kg = (lane >> 4) * 8;
  f32x4 acc[2][8];
  #pragma unroll
  for (int m = 0; m < 2; ++m)
    #pragma unroll
    for (int n = 0; n < 8; ++n) acc[m][n] = (f32x4)(0.f);
  #pragma unroll
  for (int kk = 0; kk < 4; ++kk) {
    const int kb = (kk * 32 + kg) * 2;
    s16x8 a[2], b[8];
    #pragma unroll
    for (int m = 0; m < 2; ++m) {
      int r = row0 + m * 16 + lr;
      a[m] = *(const s16x8*)(As + r * 256 + (kb ^ ((r & 7) << 4)));
    }
    #pragma unroll
    for (int n = 0; n < 8; ++n) {
      int cc = n * 16 + lr;
      b[n] = *(const s16x8*)(Bs + cc * 256 + (kb ^ ((cc & 7) << 4)));
    }
    #pragma unroll
    for (int m = 0; m < 2; ++m)
      #pragma unroll
      for (int n = 0; n < 8; ++n)
        acc[m][n] = __builtin_amdgcn_mfma_f32_16x16x32_bf16(a[m], b[n], acc[m][n], 0, 0, 0);
  }
  // epilogue: C layout col=lane&15, row=(lane>>4)*4+j
  #pragma unroll
  for (int m = 0; m < 2; ++m) {
    int rbase = mb * 128 + row0 + m * 16 + (lane >> 4) * 4;
    #pragma unroll
    for (int n = 0; n < 8; ++n) {
      int col = n * 16 + lr;
      #pragma unroll
      for (int j = 0; j < 4; ++j) {
        int grow = rbase + j;
        if (grow < N_NODES)
          X[((size_t)rel * N_NODES + grow) * 128 + col] = f2bf(acc[m][n][j]);
      }
    }
  }
}

// ---- per-node aggregation over CSR: one wave per node, 8-deep unroll ----
template <bool LAST>
__global__ void k_aggregate(const unsigned short* __restrict__ X,
                            const unsigned* __restrict__ keys,
                            const int* __restrict__ rowptr,
                            const float* __restrict__ bias,
                            void* __restrict__ out) {
  const int t = threadIdx.x;
  const int v = blockIdx.x * 4 + (t >> 6);
  const int lane = t & 63;
  const int start = rowptr[v], end = rowptr[v + 1];
  const unsigned char* Xb = (const unsigned char*)X;
  float a0 = 0.f, a1 = 0.f;
  int e = start;
  const int n8 = start + ((end - start) & ~7);
  for (; e < n8; e += 8) {
    unsigned k0 = keys[e],     k1 = keys[e + 1], k2 = keys[e + 2], k3 = keys[e + 3];
    unsigned k4 = keys[e + 4], k5 = keys[e + 5], k6 = keys[e + 6], k7 = keys[e + 7];
    unsigned p0 = *(const unsigned*)(Xb + ((size_t)k0 << 8) + lane * 4);
    unsigned p1 = *(const unsigned*)(Xb + ((size_t)k1 << 8) + lane * 4);
    unsigned p2 = *(const unsigned*)(Xb + ((size_t)k2 << 8) + lane * 4);
    unsigned p3 = *(const unsigned*)(Xb + ((size_t)k3 << 8) + lane * 4);
    unsigned p4 = *(const unsigned*)(Xb + ((size_t)k4 << 8) + lane * 4);
    unsigned p5 = *(const unsigned*)(Xb + ((size_t)k5 << 8) + lane * 4);
    unsigned p6 = *(const unsigned*)(Xb + ((size_t)k6 << 8) + lane * 4);
    unsigned p7 = *(const unsigned*)(Xb + ((size_t)k7 << 8) + lane * 4);
    a0 += __uint_as_float(p0 << 16); a1 += __uint_as_float(p0 & 0xffff0000u);
    a0 += __uint_as_float(p1 << 16); a1 += __uint_as_float(p1 & 0xffff0000u);
    a0 += __uint_as_float(p2 << 16); a1 += __uint_as_float(p2 & 0xffff0000u);
    a0 += __uint_as_float(p3 << 16); a1 += __uint_as_float(p3 & 0xffff0000u);
    a0 += __uint_as_float(p4 << 16); a1 += __uint_as_float(p4 & 0xffff0000u);
    a0 += __uint_as_float(p5 << 16); a1 += __uint_as_float(p5 & 0xffff0000u);
    a0 += __uint_as_float(p6 << 16); a1 += __uint_as_float(p6 & 0xffff0000u);
    a0 += __uint_as_float(p7 << 16); a1 += __uint_as_float(p7 & 0xffff0000u);
  }
  const int n2 = start + ((end - start) & ~1);
  for (; e < n2; e += 2) {
    unsigned k0 = keys[e], k1 = keys[e + 1];
    unsigned p0 = *(const unsigned*)(Xb + ((size_t)k0 << 8) + lane * 4);
    unsigned p1 = *(const unsigned*)(Xb + ((size_t)k1 << 8) + lane * 4);
    a0 += __uint_as_float(p0 << 16); a1 += __uint_as_float(p0 & 0xffff0000u);
    a0 += __uint_as_float(p1 << 16); a1 += __uint_as_float(p1 & 0xffff0000u);
  }
  if (e < end) {
    unsigned k0 = keys[e];
    unsigned p0 = *(const unsigned*)(Xb + ((size_t)k0 << 8) + lane * 4);
    a0 += __uint_as_float(p0 << 16); a1 += __uint_as_float(p0 & 0xffff0000u);
  }
  { // self-loop pseudo-relation row
    unsigned p = *(const unsigned*)(Xb + (((size_t)8 * N_NODES + v) << 8) + lane * 4);
    a0 += __uint_as_float(p << 16); a1 += __uint_as_float(p & 0xffff0000u);
  }
  const float2 bb = *(const float2*)(bias + lane * 2);
  a0 += bb.x; a1 += bb.y;
  if (LAST) {
    f32x2 o; o.x = a0; o.y = a1;
    __builtin_nontemporal_store(o, (f32x2*)((float*)out + (size_t)v * 128 + lane * 2));
  } else {
    unsigned po = ((unsigned)f2bf(a1) << 16) | (unsigned)f2bf(a0);
    *(unsigned*)((unsigned short*)out + (size_t)v * 128 + lane * 2) = po;
  }
}

extern "C" void kernel_launch(void* const* d_in, const int* in_sizes, int n_in,
                              void* d_out, int out_size, void* d_ws, size_t ws_size,
                              hipStream_t stream) {
  const int*   nid  = (const int*)d_in[0];
  const int*   src  = (const int*)d_in[1];
  const int*   dst  = (const int*)d_in[2];
  const int*   et   = (const int*)d_in[3];
  const float* emb  = (const float*)d_in[4];
  const float* W    = (const float*)d_in[5];
  const float* Wl   = (const float*)d_in[6];
  const float* bias = (const float*)d_in[7];

  unsigned char* ws = (unsigned char*)d_ws;
  size_t off = 0;
  auto alloc = [&](size_t bytes) {
    void* p = ws + off;
    off = (off + bytes + 255) & ~(size_t)255;
    return p;
  };
  unsigned short* X    = (unsigned short*)alloc((size_t)9 * N_NODES * HID * 2);  // 115.2 MB
  unsigned short* h0   = (unsigned short*)alloc((size_t)N_NODES * HID * 2);      // 12.8 MB
  unsigned short* h1   = (unsigned short*)alloc((size_t)N_NODES * HID * 2);      // 12.8 MB
  unsigned short* Wt   = (unsigned short*)alloc((size_t)2 * 9 * 128 * 128 * 2);  // 0.6 MB
  unsigned*       keys = (unsigned*)alloc((size_t)N_EDGES * 4);                  // 6.4 MB
  int*            rowp = (int*)alloc((size_t)(N_NODES + 1) * 4);
  int*            histT= (int*)alloc((size_t)TOT * 4);                           // 150 KB
  int*            cur  = (int*)alloc((size_t)TOT * 4);                           // 150 KB
  int*            bbas = (int*)alloc((size_t)(NB + 1) * 4);
  unsigned*       tmp  = (unsigned*)X;   // X dead during CSR build; reuse as scratch

  k_convert_w<<<1152, 256, 0, stream>>>(W, Wl, Wt);
  k_gather_h0<<<(N_NODES * 32) / 256, 256, 0, stream>>>(nid, emb, h0);
  k_chunk_hist<<<NCH, 256, 0, stream>>>(dst, histT);
  k_csr_scan<<<1, 256, 0, stream>>>(histT, cur, bbas, rowp);
  k_chunk_scatter<<<NCH, 256, 0, stream>>>(src, dst, et, cur, tmp);
  k_bucket_finalize<<<NB, 256, 0, stream>>>(tmp, bbas, rowp, keys);

  dim3 ggrid(9, (N_NODES + 127) / 128);          // 9 x 391
  const int agrid = N_NODES / 4;                 // 12500, one wave per node
  // layer 0
  k_gemm<<<ggrid, 256, 0, stream>>>(h0, Wt, X);
  k_aggregate<false><<<agrid, 256, 0, stream>>>(X, keys, rowp, bias, (void*)h1);
  // layer 1
  k_gemm<<<ggrid, 256, 0, stream>>>(h1, Wt + (size_t)9 * 128 * 128, X);
  k_aggregate<true><<<agrid, 256, 0, stream>>>(X, keys, rowp, bias + HID, (void*)d_out);
}

// Round 9
// 304.759 us; speedup vs baseline: 1.6974x; 1.2242x over previous
//
#include <hip/hip_runtime.h>
#include <stdint.h>

#define N_NODES 50000
#define N_EDGES 1600000
#define HID 128
#define NB 196      // dst buckets of 256 nodes
#define CHUNK 8192
#define NCH 196     // ceil(1600000 / 8192)
#define TOT (NB * NCH)

typedef float f32x4 __attribute__((ext_vector_type(4)));
typedef float f32x2 __attribute__((ext_vector_type(2)));
typedef short s16x8 __attribute__((ext_vector_type(8)));
typedef unsigned u32x4 __attribute__((ext_vector_type(4)));

__device__ __forceinline__ unsigned short f2bf(float f) {
  unsigned u = __float_as_uint(f);
  u += 0x7fffu + ((u >> 16) & 1u);   // RNE
  return (unsigned short)(u >> 16);
}

// ---- W transpose + convert: Wt[l][r][k][d] = W[l][r][d][k] (r=8 -> W_loop) ----
__global__ void k_convert_w(const float* __restrict__ W, const float* __restrict__ Wl,
                            unsigned short* __restrict__ Wt) {
  int idx = blockIdx.x * 256 + threadIdx.x;   // (((l*9+r)*128)+k)*128+d
  int d  = idx & 127;
  int k  = (idx >> 7) & 127;
  int lr = idx >> 14;                          // l*9 + r
  int l = lr / 9, r = lr - l * 9;
  float v;
  if (r < 8) v = W[((((size_t)l * 8 + r) * 128) + d) * 128 + k];
  else       v = Wl[(((size_t)l * 128) + d) * 128 + k];
  Wt[idx] = f2bf(v);
}

// ---- h0 = bf16(emb[node_id]) ----
__global__ void k_gather_h0(const int* __restrict__ nid, const float* __restrict__ emb,
                            unsigned short* __restrict__ h0) {
  int t = blockIdx.x * 256 + threadIdx.x;      // N*32 threads, 4 elems each
  int i = t >> 5, c = (t & 31) * 4;
  if (i >= N_NODES) return;
  const float4 v = *(const float4*)(emb + (size_t)nid[i] * HID + c);
  ushort4 o;
  o.x = f2bf(v.x); o.y = f2bf(v.y); o.z = f2bf(v.z); o.w = f2bf(v.w);
  *(ushort4*)(h0 + (size_t)i * HID + c) = o;
}

__device__ __forceinline__ int block_scan_excl(int v, int t) {
  const int lane = t & 63, wid = t >> 6;
  int incl = v;
  #pragma unroll
  for (int o = 1; o < 64; o <<= 1) {
    int nv = __shfl_up(incl, o);
    if (lane >= o) incl += nv;
  }
  __shared__ int wsum[4];
  if (lane == 63) wsum[wid] = incl;
  __syncthreads();
  int wbase = 0;
  #pragma unroll
  for (int w = 0; w < 3; ++w) if (w < wid) wbase += wsum[w];
  return wbase + incl - v;
}

// ---- CSR pass A: per-chunk bucket histogram -> TRANSPOSED store histT[b][c] ----
__global__ void k_chunk_hist(const int* __restrict__ dst, int* __restrict__ histT) {
  __shared__ int h[NB];
  const int c = blockIdx.x, t = threadIdx.x;
  if (t < NB) h[t] = 0;
  __syncthreads();
  int base = c * CHUNK;
  #pragma unroll 4
  for (int i = t; i < CHUNK; i += 256) {
    int e = base + i;
    if (e < N_EDGES) atomicAdd(&h[dst[e] >> 8], 1);
  }
  __syncthreads();
  if (t < NB) histT[t * NCH + c] = h[t];
}

// ---- CSR pass B1: per-bucket chunk-prefix scan (196 blocks, 1 wave each) ----
// curL[b][c] = sum_{c'<c} histT[b][c'];  btot[b] = bucket total
__global__ void k_scan_buckets(const int* __restrict__ histT, int* __restrict__ curL,
                               int* __restrict__ btot) {
  const int b = blockIdx.x, tid = threadIdx.x;   // 64 threads
  int carry = 0;
  #pragma unroll
  for (int k = 0; k < 4; ++k) {
    int c = k * 64 + tid;
    int v = (c < NCH) ? histT[b * NCH + c] : 0;
    int incl = v;
    #pragma unroll
    for (int o = 1; o < 64; o <<= 1) {
      int nv = __shfl_up(incl, o);
      if (tid >= o) incl += nv;
    }
    if (c < NCH) curL[b * NCH + c] = carry + incl - v;
    carry += __shfl(incl, 63);
  }
  if (tid == 0) btot[b] = carry;
}

// ---- CSR pass B2: scan 196 bucket totals -> bbase ----
__global__ void k_scan_top(const int* __restrict__ btot, int* __restrict__ bbase,
                           int* __restrict__ rowptr) {
  const int t = threadIdx.x;
  int v = (t < NB) ? btot[t] : 0;
  int ex = block_scan_excl(v, t);
  if (t < NB) bbase[t] = ex;
  if (t == 0) { bbase[NB] = N_EDGES; rowptr[N_NODES] = N_EDGES; }
}

// ---- CSR pass C: chunk-local scatter via LDS cursors (no global atomics) ----
// record = (dst&255)<<19 | et<<16 | src
__global__ void k_chunk_scatter(const int* __restrict__ src, const int* __restrict__ dst,
                                const int* __restrict__ et, const int* __restrict__ curL,
                                const int* __restrict__ bbase,
                                unsigned* __restrict__ tmp) {
  __shared__ int off2[NB];
  const int c = blockIdx.x, t = threadIdx.x;
  if (t < NB) off2[t] = curL[t * NCH + c] + bbase[t];
  __syncthreads();
  int base = c * CHUNK;
  #pragma unroll 4
  for (int i = t; i < CHUNK; i += 256) {
    int e = base + i;
    if (e < N_EDGES) {
      int d = dst[e];
      int pos = atomicAdd(&off2[d >> 8], 1);
      tmp[pos] = ((unsigned)(d & 255) << 19) | ((unsigned)et[e] << 16) | (unsigned)src[e];
    }
  }
}

// ---- CSR finalize: per-node counting sort -> rowptr + u32 keys (et*N+src) ----
__global__ void k_bucket_finalize(const unsigned* __restrict__ tmp,
                                  const int* __restrict__ bbase,
                                  int* __restrict__ rowptr,
                                  unsigned* __restrict__ keys) {
  __shared__ int cnt[256];
  __shared__ int off[256];
  const int b = blockIdx.x;
  const int t = threadIdx.x;
  const int s = bbase[b], e = bbase[b + 1];
  cnt[t] = 0;
  __syncthreads();
  for (int i = s + t; i < e; i += 256)
    atomicAdd(&cnt[(tmp[i] >> 19) & 255u], 1);
  __syncthreads();
  int ex = block_scan_excl(cnt[t], t);
  int node = b * 256 + t;
  if (node < N_NODES) rowptr[node] = s + ex;
  off[t] = s + ex;
  __syncthreads();
  for (int i = s + t; i < e; i += 256) {
    unsigned r = tmp[i];
    int pos = atomicAdd(&off[(r >> 19) & 255u], 1);
    keys[pos] = ((r >> 16) & 7u) * N_NODES + (r & 0xffffu);
  }
}

// ---- GEMM: X[rel][n][k] = sum_d A[n][d] * Wt[rel][k][d], bf16 in/out, f32 acc ----
__global__ __launch_bounds__(256, 2) void k_gemm(
    const unsigned short* __restrict__ A,   // [N][128] bf16
    const unsigned short* __restrict__ Bw,  // [9][128][128] bf16 (this layer's Wt)
    unsigned short* __restrict__ X) {       // [9][N][128] bf16
  __shared__ unsigned char lds[65536];
  unsigned char* As = lds;
  unsigned char* Bs = lds + 32768;
  const int t   = threadIdx.x;
  const int rel = blockIdx.x;
  const int mb  = blockIdx.y;
  const unsigned char* Asrc = (const unsigned char*)A;
  const unsigned char* Bsrc = (const unsigned char*)(Bw + (size_t)rel * (128 * 128));
  #pragma unroll
  for (int c = 0; c < 8; ++c) {
    int off = c * 4096 + t * 16;
    int row = off >> 8;
    int ib  = off & 255;
    int swz = ib ^ ((row & 7) << 4);
    int grow = mb * 128 + row;
    u32x4 va = (u32x4)(0u);
    if (grow < N_NODES) va = *(const u32x4*)(Asrc + (size_t)grow * 256 + ib);
    *(u32x4*)(As + row * 256 + swz) = va;
    u32x4 vb = *(const u32x4*)(Bsrc + off);
    *(u32x4*)(Bs + row * 256 + swz) = vb;
  }
  __syncthreads();
  const int wid = t >> 6, lane = t & 63;
  const int row0 = wid * 32;
  const int lr = lane & 15;
  const int kg = (lane >> 4) * 8;
  f32x4 acc[2][8];
  #pragma unroll
  for (int m = 0; m < 2; ++m)
    #pragma unroll
    for (int n = 0; n < 8; ++n) acc[m][n] = (f32x4)(0.f);
  #pragma unroll
  for (int kk = 0; kk < 4; ++kk) {
    const int kb = (kk * 32 + kg) * 2;
    s16x8 a[2], b[8];
    #pragma unroll
    for (int m = 0; m < 2; ++m) {
      int r = row0 + m * 16 + lr;
      a[m] = *(const s16x8*)(As + r * 256 + (kb ^ ((r & 7) << 4)));
    }
    #pragma unroll
    for (int n = 0; n < 8; ++n) {
      int cc = n * 16 + lr;
      b[n] = *(const s16x8*)(Bs + cc * 256 + (kb ^ ((cc & 7) << 4)));
    }
    #pragma unroll
    for (int m = 0; m < 2; ++m)
      #pragma unroll
      for (int n = 0; n < 8; ++n)
        acc[m][n] = __builtin_amdgcn_mfma_f32_16x16x32_bf16(a[m], b[n], acc[m][n], 0, 0, 0);
  }
  // epilogue: C layout col=lane&15, row=(lane>>4)*4+j
  #pragma unroll
  for (int m = 0; m < 2; ++m) {
    int rbase = mb * 128 + row0 + m * 16 + (lane >> 4) * 4;
    #pragma unroll
    for (int n = 0; n < 8; ++n) {
      int col = n * 16 + lr;
      #pragma unroll
      for (int j = 0; j < 4; ++j) {
        int grow = rbase + j;
        if (grow < N_NODES)
          X[((size_t)rel * N_NODES + grow) * 128 + col] = f2bf(acc[m][n][j]);
      }
    }
  }
}

// ---- per-node aggregation over CSR: one wave per node, 8-deep unroll ----
template <bool LAST>
__global__ void k_aggregate(const unsigned short* __restrict__ X,
                            const unsigned* __restrict__ keys,
                            const int* __restrict__ rowptr,
                            const float* __restrict__ bias,
                            void* __restrict__ out) {
  const int t = threadIdx.x;
  const int v = blockIdx.x * 4 + (t >> 6);
  const int lane = t & 63;
  const int start = rowptr[v], end = rowptr[v + 1];
  const unsigned char* Xb = (const unsigned char*)X;
  float a0 = 0.f, a1 = 0.f;
  int e = start;
  const int n8 = start + ((end - start) & ~7);
  for (; e < n8; e += 8) {
    unsigned k0 = keys[e],     k1 = keys[e + 1], k2 = keys[e + 2], k3 = keys[e + 3];
    unsigned k4 = keys[e + 4], k5 = keys[e + 5], k6 = keys[e + 6], k7 = keys[e + 7];
    unsigned p0 = *(const unsigned*)(Xb + ((size_t)k0 << 8) + lane * 4);
    unsigned p1 = *(const unsigned*)(Xb + ((size_t)k1 << 8) + lane * 4);
    unsigned p2 = *(const unsigned*)(Xb + ((size_t)k2 << 8) + lane * 4);
    unsigned p3 = *(const unsigned*)(Xb + ((size_t)k3 << 8) + lane * 4);
    unsigned p4 = *(const unsigned*)(Xb + ((size_t)k4 << 8) + lane * 4);
    unsigned p5 = *(const unsigned*)(Xb + ((size_t)k5 << 8) + lane * 4);
    unsigned p6 = *(const unsigned*)(Xb + ((size_t)k6 << 8) + lane * 4);
    unsigned p7 = *(const unsigned*)(Xb + ((size_t)k7 << 8) + lane * 4);
    a0 += __uint_as_float(p0 << 16); a1 += __uint_as_float(p0 & 0xffff0000u);
    a0 += __uint_as_float(p1 << 16); a1 += __uint_as_float(p1 & 0xffff0000u);
    a0 += __uint_as_float(p2 << 16); a1 += __uint_as_float(p2 & 0xffff0000u);
    a0 += __uint_as_float(p3 << 16); a1 += __uint_as_float(p3 & 0xffff0000u);
    a0 += __uint_as_float(p4 << 16); a1 += __uint_as_float(p4 & 0xffff0000u);
    a0 += __uint_as_float(p5 << 16); a1 += __uint_as_float(p5 & 0xffff0000u);
    a0 += __uint_as_float(p6 << 16); a1 += __uint_as_float(p6 & 0xffff0000u);
    a0 += __uint_as_float(p7 << 16); a1 += __uint_as_float(p7 & 0xffff0000u);
  }
  const int n2 = start + ((end - start) & ~1);
  for (; e < n2; e += 2) {
    unsigned k0 = keys[e], k1 = keys[e + 1];
    unsigned p0 = *(const unsigned*)(Xb + ((size_t)k0 << 8) + lane * 4);
    unsigned p1 = *(const unsigned*)(Xb + ((size_t)k1 << 8) + lane * 4);
    a0 += __uint_as_float(p0 << 16); a1 += __uint_as_float(p0 & 0xffff0000u);
    a0 += __uint_as_float(p1 << 16); a1 += __uint_as_float(p1 & 0xffff0000u);
  }
  if (e < end) {
    unsigned k0 = keys[e];
    unsigned p0 = *(const unsigned*)(Xb + ((size_t)k0 << 8) + lane * 4);
    a0 += __uint_as_float(p0 << 16); a1 += __uint_as_float(p0 & 0xffff0000u);
  }
  { // self-loop pseudo-relation row
    unsigned p = *(const unsigned*)(Xb + (((size_t)8 * N_NODES + v) << 8) + lane * 4);
    a0 += __uint_as_float(p << 16); a1 += __uint_as_float(p & 0xffff0000u);
  }
  const float2 bb = *(const float2*)(bias + lane * 2);
  a0 += bb.x; a1 += bb.y;
  if (LAST) {
    f32x2 o; o.x = a0; o.y = a1;
    __builtin_nontemporal_store(o, (f32x2*)((float*)out + (size_t)v * 128 + lane * 2));
  } else {
    unsigned po = ((unsigned)f2bf(a1) << 16) | (unsigned)f2bf(a0);
    *(unsigned*)((unsigned short*)out + (size_t)v * 128 + lane * 2) = po;
  }
}

extern "C" void kernel_launch(void* const* d_in, const int* in_sizes, int n_in,
                              void* d_out, int out_size, void* d_ws, size_t ws_size,
                              hipStream_t stream) {
  const int*   nid  = (const int*)d_in[0];
  const int*   src  = (const int*)d_in[1];
  const int*   dst  = (const int*)d_in[2];
  const int*   et   = (const int*)d_in[3];
  const float* emb  = (const float*)d_in[4];
  const float* W    = (const float*)d_in[5];
  const float* Wl   = (const float*)d_in[6];
  const float* bias = (const float*)d_in[7];

  unsigned char* ws = (unsigned char*)d_ws;
  size_t off = 0;
  auto alloc = [&](size_t bytes) {
    void* p = ws + off;
    off = (off + bytes + 255) & ~(size_t)255;
    return p;
  };
  unsigned short* X    = (unsigned short*)alloc((size_t)9 * N_NODES * HID * 2);  // 115.2 MB
  unsigned short* h0   = (unsigned short*)alloc((size_t)N_NODES * HID * 2);      // 12.8 MB
  unsigned short* h1   = (unsigned short*)alloc((size_t)N_NODES * HID * 2);      // 12.8 MB
  unsigned short* Wt   = (unsigned short*)alloc((size_t)2 * 9 * 128 * 128 * 2);  // 0.6 MB
  unsigned*       keys = (unsigned*)alloc((size_t)N_EDGES * 4);                  // 6.4 MB
  int*            rowp = (int*)alloc((size_t)(N_NODES + 1) * 4);
  int*            histT= (int*)alloc((size_t)TOT * 4);                           // 150 KB
  int*            curL = (int*)alloc((size_t)TOT * 4);                           // 150 KB
  int*            btot = (int*)alloc((size_t)NB * 4);
  int*            bbas = (int*)alloc((size_t)(NB + 1) * 4);
  unsigned*       tmp  = (unsigned*)X;   // X dead during CSR build; reuse as scratch

  k_convert_w<<<1152, 256, 0, stream>>>(W, Wl, Wt);
  k_gather_h0<<<(N_NODES * 32) / 256, 256, 0, stream>>>(nid, emb, h0);
  k_chunk_hist<<<NCH, 256, 0, stream>>>(dst, histT);
  k_scan_buckets<<<NB, 64, 0, stream>>>(histT, curL, btot);
  k_scan_top<<<1, 256, 0, stream>>>(btot, bbas, rowp);
  k_chunk_scatter<<<NCH, 256, 0, stream>>>(src, dst, et, curL, bbas, tmp);
  k_bucket_finalize<<<NB, 256, 0, stream>>>(tmp, bbas, rowp, keys);

  dim3 ggrid(9, (N_NODES + 127) / 128);          // 9 x 391
  const int agrid = N_NODES / 4;                 // 12500, one wave per node
  // layer 0
  k_gemm<<<ggrid, 256, 0, stream>>>(h0, Wt, X);
  k_aggregate<false><<<agrid, 256, 0, stream>>>(X, keys, rowp, bias, (void*)h1);
  // layer 1
  k_gemm<<<ggrid, 256, 0, stream>>>(h1, Wt + (size_t)9 * 128 * 128, X);
  k_aggregate<true><<<agrid, 256, 0, stream>>>(X, keys, rowp, bias + HID, (void*)d_out);
}

// Round 10
// 265.225 us; speedup vs baseline: 1.9504x; 1.1491x over previous
//
#include <hip/hip_runtime.h>
#include <stdint.h>

#define N_NODES 50000
#define N_EDGES 1600000
#define HID 128
#define NB 196      // dst buckets of 256 nodes
#define CHUNK 8192
#define NCH 196     // ceil(1600000 / 8192)
#define TOT (NB * NCH)
#define NGB 6250    // gather_h0 blocks (N*32/256)
#define NCW 1152    // convert_w blocks
#define NMB 782     // gemm 64-row tiles

typedef float f32x4 __attribute__((ext_vector_type(4)));
typedef float f32x2 __attribute__((ext_vector_type(2)));
typedef short s16x8 __attribute__((ext_vector_type(8)));
typedef unsigned u32x4 __attribute__((ext_vector_type(4)));

__device__ __forceinline__ unsigned short f2bf(float f) {
  unsigned u = __float_as_uint(f);
  u += 0x7fffu + ((u >> 16) & 1u);   // RNE
  return (unsigned short)(u >> 16);
}

__device__ __forceinline__ int block_scan_excl(int v, int t) {
  const int lane = t & 63, wid = t >> 6;
  int incl = v;
  #pragma unroll
  for (int o = 1; o < 64; o <<= 1) {
    int nv = __shfl_up(incl, o);
    if (lane >= o) incl += nv;
  }
  __shared__ int wsum[4];
  if (lane == 63) wsum[wid] = incl;
  __syncthreads();
  int wbase = 0;
  #pragma unroll
  for (int w = 0; w < 3; ++w) if (w < wid) wbase += wsum[w];
  return wbase + incl - v;
}

// ---- pre-kernel: gather_h0 (blocks 0..6249) | chunk_hist (6250..6445) |
// ----              convert_w (6446..7597) ----
__global__ void k_pre(const int* __restrict__ nid, const float* __restrict__ emb,
                      unsigned short* __restrict__ h0,
                      const int* __restrict__ dst, int* __restrict__ histT,
                      const float* __restrict__ W, const float* __restrict__ Wl,
                      unsigned short* __restrict__ Wt) {
  const int bid = blockIdx.x, t = threadIdx.x;
  if (bid < NGB) {                       // h0 = bf16(emb[node_id])
    int g = bid * 256 + t;
    int i = g >> 5, c = (g & 31) * 4;
    const float4 v = *(const float4*)(emb + (size_t)nid[i] * HID + c);
    ushort4 o;
    o.x = f2bf(v.x); o.y = f2bf(v.y); o.z = f2bf(v.z); o.w = f2bf(v.w);
    *(ushort4*)(h0 + (size_t)i * HID + c) = o;
  } else if (bid < NGB + NCH) {          // per-chunk bucket histogram
    __shared__ int h[NB];
    const int c = bid - NGB;
    if (t < NB) h[t] = 0;
    __syncthreads();
    int base = c * CHUNK;
    #pragma unroll 4
    for (int i = t; i < CHUNK; i += 256) {
      int e = base + i;
      if (e < N_EDGES) atomicAdd(&h[dst[e] >> 8], 1);
    }
    __syncthreads();
    if (t < NB) histT[t * NCH + c] = h[t];
  } else {                               // Wt[l][r][k][d] = W[l][r][d][k]
    int idx = (bid - NGB - NCH) * 256 + t;
    int d  = idx & 127;
    int k  = (idx >> 7) & 127;
    int lr = idx >> 14;
    int l = lr / 9, r = lr - l * 9;
    float v;
    if (r < 8) v = W[((((size_t)l * 8 + r) * 128) + d) * 128 + k];
    else       v = Wl[(((size_t)l * 128) + d) * 128 + k];
    Wt[idx] = f2bf(v);
  }
}

// ---- CSR pass B1: per-bucket chunk-prefix scan (196 blocks, 1 wave each) ----
__global__ void k_scan_buckets(const int* __restrict__ histT, int* __restrict__ curL,
                               int* __restrict__ btot) {
  const int b = blockIdx.x, tid = threadIdx.x;   // 64 threads
  int carry = 0;
  #pragma unroll
  for (int k = 0; k < 4; ++k) {
    int c = k * 64 + tid;
    int v = (c < NCH) ? histT[b * NCH + c] : 0;
    int incl = v;
    #pragma unroll
    for (int o = 1; o < 64; o <<= 1) {
      int nv = __shfl_up(incl, o);
      if (tid >= o) incl += nv;
    }
    if (c < NCH) curL[b * NCH + c] = carry + incl - v;
    carry += __shfl(incl, 63);
  }
  if (tid == 0) btot[b] = carry;
}

// ---- CSR pass B2: scan 196 bucket totals -> bbase ----
__global__ void k_scan_top(const int* __restrict__ btot, int* __restrict__ bbase,
                           int* __restrict__ rowptr) {
  const int t = threadIdx.x;
  int v = (t < NB) ? btot[t] : 0;
  int ex = block_scan_excl(v, t);
  if (t < NB) bbase[t] = ex;
  if (t == 0) { bbase[NB] = N_EDGES; rowptr[N_NODES] = N_EDGES; }
}

// ---- GEMM (all 9 rels per mb-tile, A staged once) | optional scatter role ----
// X[rel][n][k] = sum_d A[n][d] * Wt[rel][k][d]
template <bool SCAT>
__global__ __launch_bounds__(256, 3) void k_gemm9(
    const unsigned short* __restrict__ A,   // [N][128] bf16
    const unsigned short* __restrict__ Bw,  // [9][128][128] bf16 (this layer)
    unsigned short* __restrict__ X,         // [9][N][128] bf16
    const int* __restrict__ src, const int* __restrict__ dst,
    const int* __restrict__ et, const int* __restrict__ curL,
    const int* __restrict__ bbase, unsigned* __restrict__ tmp) {
  __shared__ unsigned char As[16384];   // 64 rows x 256B
  __shared__ unsigned char Ws[32768];   // 128 rows x 256B
  const int t = threadIdx.x;
  if (SCAT && blockIdx.x >= NMB) {      // chunk-local scatter role
    __shared__ int off2[NB];
    const int c = blockIdx.x - NMB;
    if (t < NB) off2[t] = curL[t * NCH + c] + bbase[t];
    __syncthreads();
    int base = c * CHUNK;
    #pragma unroll 4
    for (int i = t; i < CHUNK; i += 256) {
      int e = base + i;
      if (e < N_EDGES) {
        int d = dst[e];
        int pos = atomicAdd(&off2[d >> 8], 1);
        tmp[pos] = ((unsigned)(d & 255) << 19) | ((unsigned)et[e] << 16) | (unsigned)src[e];
      }
    }
    return;
  }
  const int mb = blockIdx.x;
  const int wid = t >> 6, lane = t & 63;
  const int lr = lane & 15, kg = (lane >> 4) * 8;
  // stage A-tile once (16KB), swizzled
  const unsigned char* Asrc = (const unsigned char*)A;
  #pragma unroll
  for (int c = 0; c < 4; ++c) {
    int off = c * 4096 + t * 16;
    int row = off >> 8, ib = off & 255;
    int grow = mb * 64 + row;
    u32x4 va = (u32x4)(0u);
    if (grow < N_NODES) va = *(const u32x4*)(Asrc + (size_t)grow * 256 + ib);
    *(u32x4*)(As + row * 256 + (ib ^ ((row & 7) << 4))) = va;
  }
  for (int rel = 0; rel < 9; ++rel) {
    // stage W_rel (32KB), swizzled
    const unsigned char* Bsrc = (const unsigned char*)(Bw + (size_t)rel * 16384);
    #pragma unroll
    for (int c = 0; c < 8; ++c) {
      int off = c * 4096 + t * 16;
      int row = off >> 8, ib = off & 255;
      *(u32x4*)(Ws + row * 256 + (ib ^ ((row & 7) << 4))) = *(const u32x4*)(Bsrc + off);
    }
    __syncthreads();
    f32x4 acc[8];
    #pragma unroll
    for (int n = 0; n < 8; ++n) acc[n] = (f32x4)(0.f);
    #pragma unroll
    for (int kk = 0; kk < 4; ++kk) {
      const int kb = (kk * 32 + kg) * 2;
      const int rA = wid * 16 + lr;
      s16x8 a = *(const s16x8*)(As + rA * 256 + (kb ^ ((rA & 7) << 4)));
      #pragma unroll
      for (int n = 0; n < 8; ++n) {
        int cc = n * 16 + lr;
        s16x8 b = *(const s16x8*)(Ws + cc * 256 + (kb ^ ((cc & 7) << 4)));
        acc[n] = __builtin_amdgcn_mfma_f32_16x16x32_bf16(a, b, acc[n], 0, 0, 0);
      }
    }
    // epilogue: C layout col=lane&15, row=(lane>>4)*4+j
    const int rbase = mb * 64 + wid * 16 + (lane >> 4) * 4;
    #pragma unroll
    for (int n = 0; n < 8; ++n) {
      int col = n * 16 + lr;
      #pragma unroll
      for (int j = 0; j < 4; ++j) {
        int grow = rbase + j;
        if (grow < N_NODES)
          X[((size_t)rel * N_NODES + grow) * 128 + col] = f2bf(acc[n][j]);
      }
    }
    __syncthreads();   // all waves done with Ws before restage
  }
}

// ---- CSR finalize: per-node counting sort -> rowptr + u32 keys (et*N+src) ----
__global__ void k_bucket_finalize(const unsigned* __restrict__ tmp,
                                  const int* __restrict__ bbase,
                                  int* __restrict__ rowptr,
                                  unsigned* __restrict__ keys) {
  __shared__ int cnt[256];
  __shared__ int off[256];
  const int b = blockIdx.x;
  const int t = threadIdx.x;
  const int s = bbase[b], e = bbase[b + 1];
  cnt[t] = 0;
  __syncthreads();
  for (int i = s + t; i < e; i += 256)
    atomicAdd(&cnt[(tmp[i] >> 19) & 255u], 1);
  __syncthreads();
  int ex = block_scan_excl(cnt[t], t);
  int node = b * 256 + t;
  if (node < N_NODES) rowptr[node] = s + ex;
  off[t] = s + ex;
  __syncthreads();
  for (int i = s + t; i < e; i += 256) {
    unsigned r = tmp[i];
    int pos = atomicAdd(&off[(r >> 19) & 255u], 1);
    keys[pos] = ((r >> 16) & 7u) * N_NODES + (r & 0xffffu);
  }
}

// ---- per-node aggregation over CSR: one wave per node, 16-deep unroll ----
template <bool LAST>
__global__ void k_aggregate(const unsigned short* __restrict__ X,
                            const unsigned* __restrict__ keys,
                            const int* __restrict__ rowptr,
                            const float* __restrict__ bias,
                            void* __restrict__ out) {
  const int t = threadIdx.x;
  const int v = blockIdx.x * 4 + (t >> 6);
  const int lane = t & 63;
  const int start = rowptr[v], end = rowptr[v + 1];
  const unsigned char* Xb = (const unsigned char*)X;
  float a0 = 0.f, a1 = 0.f;
  int e = start;
  const int n16 = start + ((end - start) & ~15);
  for (; e < n16; e += 16) {
    unsigned kk[16], pp[16];
    #pragma unroll
    for (int q = 0; q < 16; ++q) kk[q] = keys[e + q];
    #pragma unroll
    for (int q = 0; q < 16; ++q)
      pp[q] = *(const unsigned*)(Xb + ((size_t)kk[q] << 8) + lane * 4);
    #pragma unroll
    for (int q = 0; q < 16; ++q) {
      a0 += __uint_as_float(pp[q] << 16);
      a1 += __uint_as_float(pp[q] & 0xffff0000u);
    }
  }
  const int n4 = start + ((end - start) & ~3);
  for (; e < n4; e += 4) {
    unsigned kk[4], pp[4];
    #pragma unroll
    for (int q = 0; q < 4; ++q) kk[q] = keys[e + q];
    #pragma unroll
    for (int q = 0; q < 4; ++q)
      pp[q] = *(const unsigned*)(Xb + ((size_t)kk[q] << 8) + lane * 4);
    #pragma unroll
    for (int q = 0; q < 4; ++q) {
      a0 += __uint_as_float(pp[q] << 16);
      a1 += __uint_as_float(pp[q] & 0xffff0000u);
    }
  }
  for (; e < end; ++e) {
    unsigned k0 = keys[e];
    unsigned p0 = *(const unsigned*)(Xb + ((size_t)k0 << 8) + lane * 4);
    a0 += __uint_as_float(p0 << 16); a1 += __uint_as_float(p0 & 0xffff0000u);
  }
  { // self-loop pseudo-relation row
    unsigned p = *(const unsigned*)(Xb + (((size_t)8 * N_NODES + v) << 8) + lane * 4);
    a0 += __uint_as_float(p << 16); a1 += __uint_as_float(p & 0xffff0000u);
  }
  const float2 bb = *(const float2*)(bias + lane * 2);
  a0 += bb.x; a1 += bb.y;
  if (LAST) {
    f32x2 o; o.x = a0; o.y = a1;
    __builtin_nontemporal_store(o, (f32x2*)((float*)out + (size_t)v * 128 + lane * 2));
  } else {
    unsigned po = ((unsigned)f2bf(a1) << 16) | (unsigned)f2bf(a0);
    *(unsigned*)((unsigned short*)out + (size_t)v * 128 + lane * 2) = po;
  }
}

extern "C" void kernel_launch(void* const* d_in, const int* in_sizes, int n_in,
                              void* d_out, int out_size, void* d_ws, size_t ws_size,
                              hipStream_t stream) {
  const int*   nid  = (const int*)d_in[0];
  const int*   src  = (const int*)d_in[1];
  const int*   dst  = (const int*)d_in[2];
  const int*   et   = (const int*)d_in[3];
  const float* emb  = (const float*)d_in[4];
  const float* W    = (const float*)d_in[5];
  const float* Wl   = (const float*)d_in[6];
  const float* bias = (const float*)d_in[7];

  unsigned char* ws = (unsigned char*)d_ws;
  size_t off = 0;
  auto alloc = [&](size_t bytes) {
    void* p = ws + off;
    off = (off + bytes + 255) & ~(size_t)255;
    return p;
  };
  unsigned short* X    = (unsigned short*)alloc((size_t)9 * N_NODES * HID * 2);  // 115.2 MB
  unsigned short* h0   = (unsigned short*)alloc((size_t)N_NODES * HID * 2);      // 12.8 MB
  unsigned short* h1   = (unsigned short*)alloc((size_t)N_NODES * HID * 2);      // 12.8 MB
  unsigned short* Wt   = (unsigned short*)alloc((size_t)2 * 9 * 128 * 128 * 2);  // 0.6 MB
  unsigned*       keys = (unsigned*)alloc((size_t)N_EDGES * 4);                  // 6.4 MB
  int*            rowp = (int*)alloc((size_t)(N_NODES + 1) * 4);
  int*            histT= (int*)alloc((size_t)TOT * 4);                           // 150 KB
  int*            curL = (int*)alloc((size_t)TOT * 4);                           // 150 KB
  int*            btot = (int*)alloc((size_t)NB * 4);
  int*            bbas = (int*)alloc((size_t)(NB + 1) * 4);
  // scatter tmp aliases h1 (dead until aggregate-L0), so it can run alongside
  // gemm-L0 which writes X
  unsigned*       tmp  = (unsigned*)h1;

  k_pre<<<NGB + NCH + NCW, 256, 0, stream>>>(nid, emb, h0, dst, histT, W, Wl, Wt);
  k_scan_buckets<<<NB, 64, 0, stream>>>(histT, curL, btot);
  k_scan_top<<<1, 256, 0, stream>>>(btot, bbas, rowp);
  // gemm layer 0 (782 blocks) + chunk_scatter (196 blocks) fused
  k_gemm9<true><<<NMB + NCH, 256, 0, stream>>>(h0, Wt, X, src, dst, et, curL, bbas, tmp);
  k_bucket_finalize<<<NB, 256, 0, stream>>>(tmp, bbas, rowp, keys);

  const int agrid = N_NODES / 4;                 // 12500, one wave per node
  k_aggregate<false><<<agrid, 256, 0, stream>>>(X, keys, rowp, bias, (void*)h1);
  k_gemm9<false><<<NMB, 256, 0, stream>>>(h1, Wt + (size_t)9 * 128 * 128, X,
                                          src, dst, et, curL, bbas, tmp);
  k_aggregate<true><<<agrid, 256, 0, stream>>>(X, keys, rowp, bias + HID, (void*)d_out);
}